// Round 8
// baseline (209.471 us; speedup 1.0000x reference)
//
#include <hip/hip_runtime.h>
#include <math.h>

#define D_GNN 256
#define ATTN  64
#define KNEI  16
#define NROWS 65536
#define NNODES 100000
#define BROWS 128

constexpr float EPSV  = 1e-6f;
constexpr float SCALE = 0.125f;   // 64^-0.5

typedef __attribute__((ext_vector_type(8))) short bf16x8;
typedef __attribute__((ext_vector_type(4))) short bf16x4;
typedef __attribute__((ext_vector_type(4))) float f32x4;

__device__ __forceinline__ unsigned short f2bf(float f) {
    union { float f; unsigned u; } v; v.f = f;
    return (unsigned short)((v.u + 0x7FFFu + ((v.u >> 16) & 1u)) >> 16);
}
__device__ __forceinline__ float bf2f(unsigned short h) {
    union { unsigned u; float f; } v; v.u = ((unsigned)h) << 16;
    return v.f;
}

typedef __attribute__((address_space(3))) short lds_short;
typedef __attribute__((address_space(1))) const short gm_short;
__device__ __forceinline__ void gload16(const unsigned short* g, short* l) {
    __builtin_amdgcn_global_load_lds((gm_short*)g, (lds_short*)l, 16, 0, 0);
}

// ---------------------------------------------------------------------------
// prep: fp32 -> bf16 (all_embs)
// ---------------------------------------------------------------------------
__global__ __launch_bounds__(256) void conv_bf16(const float* __restrict__ in,
                                                 unsigned short* __restrict__ out) {
    size_t i = (size_t)blockIdx.x * 256 + threadIdx.x;
    float4 v = ((const float4*)in)[i];
    short4 o;
    o.x = (short)f2bf(v.x); o.y = (short)f2bf(v.y);
    o.z = (short)f2bf(v.z); o.w = (short)f2bf(v.w);
    ((short4*)out)[i] = o;
}

// Mt[j][i] = (Wq @ Wk^T)[i][j] bf16 (transposed: out-col rows, K-contig)
__global__ __launch_bounds__(256) void build_Mt(const float* __restrict__ Wq,
                                                const float* __restrict__ Wk,
                                                unsigned short* __restrict__ Mt) {
    __shared__ float wq[ATTN];
    int i = blockIdx.x;
    int j = threadIdx.x;
    if (j < ATTN) wq[j] = Wq[i * ATTN + j];
    __syncthreads();
    float s = 0.f;
#pragma unroll
    for (int a = 0; a < ATTN; ++a) s = fmaf(wq[a], Wk[j * ATTN + a], s);
    Mt[j * D_GNN + i] = f2bf(s);
}

// WgT[j][k] = Wg[k][j] bf16
__global__ __launch_bounds__(256) void conv_WgT(const float* __restrict__ Wg,
                                                unsigned short* __restrict__ WgT) {
    int k = blockIdx.x;
    int j = threadIdx.x;
    WgT[j * 512 + k] = f2bf(Wg[k * D_GNN + j]);
}

// ---------------------------------------------------------------------------
// MEGA: per 128-row block: Clds fill -> P-GEMM -> gather/attn -> gate-GEMM.
// Dynamic LDS 160 KB: Clds[128*256] | PWlds[128*256] | U[16384 shorts]
// U = B-tile staging (32 KB) during GEMMs, gather stage (8 waves x 4 KB) else.
// ---------------------------------------------------------------------------
__global__ __launch_bounds__(512) void mega(const float* __restrict__ C32,
                                            const unsigned short* __restrict__ allEbf,
                                            const int* __restrict__ nidx,
                                            const float* __restrict__ nw,
                                            const unsigned short* __restrict__ Mt,
                                            const unsigned short* __restrict__ WgT,
                                            const float* __restrict__ bg,
                                            float* __restrict__ Out) {
    extern __shared__ __align__(16) short lds[];
    short* Clds  = lds;            // 32768 shorts = 64 KB
    short* PWlds = lds + 32768;    // 64 KB
    short* U     = lds + 65536;    // 16384 shorts = 32 KB

    const int tid  = threadIdx.x;
    const int lane = tid & 63;
    const int wid  = tid >> 6;
    const int wr   = wid >> 2, wc = wid & 3;     // 2 x 4 wave grid
    const int l15  = lane & 15, lg = lane >> 4;
    const int half = lane >> 5, hl = lane & 31;
    const int brow = blockIdx.x * BROWS;

    // ---- phase 0: Clds = bf16(C32 rows) ----
#pragma unroll
    for (int is = 0; is < 8; ++is) {
        int offsh = is * 4096 + tid * 8;
        size_t gp = (size_t)brow * D_GNN + offsh;
        float4 v0 = *(const float4*)(C32 + gp);
        float4 v1 = *(const float4*)(C32 + gp + 4);
        bf16x8 h;
        h[0] = (short)f2bf(v0.x); h[1] = (short)f2bf(v0.y);
        h[2] = (short)f2bf(v0.z); h[3] = (short)f2bf(v0.w);
        h[4] = (short)f2bf(v1.x); h[5] = (short)f2bf(v1.y);
        h[6] = (short)f2bf(v1.z); h[7] = (short)f2bf(v1.w);
        *(bf16x8*)&Clds[offsh] = h;
    }
    __syncthreads();

    // ---- phase 1: P = C @ Mt^T -> PWlds ----
    {
        f32x4 acc[4][4] = {};
        for (int k0 = 0; k0 < D_GNN; k0 += 64) {
#pragma unroll
            for (int is = 0; is < 4; ++is) {
                int off  = is * 8192 + tid * 16;   // bytes in 32 KB tile
                int row  = off >> 7;
                int cs   = (off & 127) >> 1;
                int lofs = is * 4096 + wid * 512;  // shorts, wave-uniform
                gload16(Mt + (size_t)row * D_GNN + k0 + cs, U + lofs);
            }
            __syncthreads();
#pragma unroll
            for (int kk = 0; kk < 64; kk += 32) {
                bf16x8 af[4], bq[4];
#pragma unroll
                for (int m = 0; m < 4; ++m)
                    af[m] = *(const bf16x8*)&Clds[(wr * 64 + m * 16 + l15) * 256 + k0 + kk + lg * 8];
#pragma unroll
                for (int n = 0; n < 4; ++n)
                    bq[n] = *(const bf16x8*)&U[(wc * 64 + n * 16 + l15) * 64 + kk + lg * 8];
#pragma unroll
                for (int m = 0; m < 4; ++m)
#pragma unroll
                    for (int n = 0; n < 4; ++n)
                        acc[m][n] = __builtin_amdgcn_mfma_f32_16x16x32_bf16(af[m], bq[n], acc[m][n], 0, 0, 0);
            }
            __syncthreads();
        }
#pragma unroll
        for (int m = 0; m < 4; ++m) {
            int row0 = wr * 64 + m * 16 + lg * 4;
#pragma unroll
            for (int n = 0; n < 4; ++n) {
                int col = wc * 64 + n * 16 + l15;
#pragma unroll
                for (int r = 0; r < 4; ++r)
                    PWlds[(row0 + r) * 256 + col] = f2bf(acc[m][n][r]);
            }
        }
    }
    __syncthreads();

    // ---- phase 2: gather + scores + softmax + weighted sum (in-place P->W) ----
    {
        short* st = U + wid * 2048;   // 4 KB per wave
        for (int p = 0; p < 16; ++p) {
            int r    = wid * 16 + p;
            int grow = brow + r;
            int   idxv = nidx[grow * KNEI + l15];
            float nwv  = nw[grow * KNEI + l15];
            // sub-pass A: neighbors 0..7 (2 per instr: lanes 0-31 / 32-63)
#pragma unroll
            for (int t = 0; t < 4; ++t) {
                int idx = __shfl(idxv, 2 * t + half, 16);
                gload16(allEbf + (size_t)idx * D_GNN + hl * 8, st + t * 512);
            }
            bf16x4 pv4 = *(const bf16x4*)&PWlds[r * 256 + lane * 4];
            float pv[4];
#pragma unroll
            for (int j = 0; j < 4; ++j) pv[j] = bf2f((unsigned short)pv4[j]);
            asm volatile("s_waitcnt vmcnt(0)" ::: "memory");
            __builtin_amdgcn_sched_barrier(0);
            float  sc[KNEI];
            bf16x4 nvA[8];
#pragma unroll
            for (int k = 0; k < 8; ++k) {
                bf16x4 v = *(const bf16x4*)&st[(k >> 1) * 512 + (k & 1) * 256 + lane * 4];
                nvA[k] = v;
                float s = 0.f;
#pragma unroll
                for (int j = 0; j < 4; ++j) s = fmaf(bf2f((unsigned short)v[j]), pv[j], s);
                sc[k] = s;
            }
            asm volatile("s_waitcnt lgkmcnt(0)" ::: "memory");
            __builtin_amdgcn_sched_barrier(0);
            // sub-pass B: neighbors 8..15 into the same slots
#pragma unroll
            for (int t = 0; t < 4; ++t) {
                int idx = __shfl(idxv, 8 + 2 * t + half, 16);
                gload16(allEbf + (size_t)idx * D_GNN + hl * 8, st + t * 512);
            }
            asm volatile("s_waitcnt vmcnt(0)" ::: "memory");
            __builtin_amdgcn_sched_barrier(0);
#pragma unroll
            for (int k = 8; k < 16; ++k) {
                bf16x4 v = *(const bf16x4*)&st[((k - 8) >> 1) * 512 + ((k - 8) & 1) * 256 + lane * 4];
                float s = 0.f;
#pragma unroll
                for (int j = 0; j < 4; ++j) s = fmaf(bf2f((unsigned short)v[j]), pv[j], s);
                sc[k] = s;
            }
            // 64-lane reduce-scatter over bits {5,4,3,2}: k(lane) = (lane>>2)&15
            float t8[8];
#pragma unroll
            for (int j = 0; j < 8; ++j) {
                float send = (lane & 32) ? sc[j] : sc[j + 8];
                float keep = (lane & 32) ? sc[j + 8] : sc[j];
                t8[j] = keep + __shfl_xor(send, 32);
            }
            float t4[4];
#pragma unroll
            for (int j = 0; j < 4; ++j) {
                float send = (lane & 16) ? t8[j] : t8[j + 4];
                float keep = (lane & 16) ? t8[j + 4] : t8[j];
                t4[j] = keep + __shfl_xor(send, 16);
            }
            float t2[2];
#pragma unroll
            for (int j = 0; j < 2; ++j) {
                float send = (lane & 8) ? t4[j] : t4[j + 2];
                float keep = (lane & 8) ? t4[j + 2] : t4[j];
                t2[j] = keep + __shfl_xor(send, 8);
            }
            float s1;
            {
                float send = (lane & 4) ? t2[0] : t2[1];
                float keep = (lane & 4) ? t2[1] : t2[0];
                s1 = keep + __shfl_xor(send, 4);
            }
            s1 += __shfl_xor(s1, 1);
            s1 += __shfl_xor(s1, 2);
            int kid = (lane >> 2) & 15;
            float w = __shfl(nwv, kid, 16);
            float s = (w < EPSV) ? -INFINITY : fmaf(s1, SCALE, logf(w));
            float mx = s;
            mx = fmaxf(mx, __shfl_xor(mx, 4));
            mx = fmaxf(mx, __shfl_xor(mx, 8));
            mx = fmaxf(mx, __shfl_xor(mx, 16));
            mx = fmaxf(mx, __shfl_xor(mx, 32));
            float e = (mx > -INFINITY) ? expf(s - mx) : 0.f;
            float den = e;
            den += __shfl_xor(den, 4);
            den += __shfl_xor(den, 8);
            den += __shfl_xor(den, 16);
            den += __shfl_xor(den, 32);
            float a = (mx > -INFINITY) ? e / den : 0.f;
            // weighted sum: lane owns cols lane*4..+3
            float acc4[4] = {};
#pragma unroll
            for (int k = 0; k < 8; ++k) {
                float ak = __shfl(a, 4 * k);
#pragma unroll
                for (int j = 0; j < 4; ++j)
                    acc4[j] = fmaf(ak, bf2f((unsigned short)nvA[k][j]), acc4[j]);
            }
#pragma unroll
            for (int k = 8; k < 16; ++k) {
                float ak = __shfl(a, 4 * k);
                bf16x4 v = *(const bf16x4*)&st[((k - 8) >> 1) * 512 + ((k - 8) & 1) * 256 + lane * 4];
#pragma unroll
                for (int j = 0; j < 4; ++j)
                    acc4[j] = fmaf(ak, bf2f((unsigned short)v[j]), acc4[j]);
            }
            bf16x4 o;
#pragma unroll
            for (int j = 0; j < 4; ++j) o[j] = (short)f2bf(acc4[j]);
            *(bf16x4*)&PWlds[r * 256 + lane * 4] = o;
        }
    }
    __syncthreads();

    // ---- phase 3: gate GEMM (K=512: C half then W half) + epilogue ----
    {
        f32x4 acc[4][4] = {};
        for (int k0 = 0; k0 < 2 * D_GNN; k0 += 64) {
            const short* Alds = (k0 < D_GNN) ? Clds : PWlds;
            int koff = k0 & (D_GNN - 1);
#pragma unroll
            for (int is = 0; is < 4; ++is) {
                int off  = is * 8192 + tid * 16;
                int row  = off >> 7;
                int cs   = (off & 127) >> 1;
                int lofs = is * 4096 + wid * 512;
                gload16(WgT + (size_t)row * 512 + k0 + cs, U + lofs);
            }
            __syncthreads();
#pragma unroll
            for (int kk = 0; kk < 64; kk += 32) {
                bf16x8 af[4], bq[4];
#pragma unroll
                for (int m = 0; m < 4; ++m)
                    af[m] = *(const bf16x8*)&Alds[(wr * 64 + m * 16 + l15) * 256 + koff + kk + lg * 8];
#pragma unroll
                for (int n = 0; n < 4; ++n)
                    bq[n] = *(const bf16x8*)&U[(wc * 64 + n * 16 + l15) * 64 + kk + lg * 8];
#pragma unroll
                for (int m = 0; m < 4; ++m)
#pragma unroll
                    for (int n = 0; n < 4; ++n)
                        acc[m][n] = __builtin_amdgcn_mfma_f32_16x16x32_bf16(af[m], bq[n], acc[m][n], 0, 0, 0);
            }
            __syncthreads();
        }
#pragma unroll
        for (int m = 0; m < 4; ++m) {
            int row0 = wr * 64 + m * 16 + lg * 4;
#pragma unroll
            for (int n = 0; n < 4; ++n) {
                int col = wc * 64 + n * 16 + l15;
                float bgc = bg[col];
#pragma unroll
                for (int r = 0; r < 4; ++r) {
                    int row = row0 + r;
                    float g  = 1.f / (1.f + expf(-(acc[m][n][r] + bgc)));
                    float cv = bf2f((unsigned short)Clds[row * 256 + col]);
                    float wv = bf2f((unsigned short)PWlds[row * 256 + col]);
                    Out[(size_t)(brow + row) * D_GNN + col] = fmaf(g, cv - wv, wv);
                }
            }
        }
    }
}

// ---------------------------------------------------------------------------
extern "C" void kernel_launch(void* const* d_in, const int* in_sizes, int n_in,
                              void* d_out, int out_size, void* d_ws, size_t ws_size,
                              hipStream_t stream) {
    const float* center = (const float*)d_in[0];
    const float* allE   = (const float*)d_in[1];
    const int*   nidx   = (const int*)d_in[2];
    const float* nw     = (const float*)d_in[3];
    const float* Wq     = (const float*)d_in[4];
    const float* Wk     = (const float*)d_in[5];
    const float* Wg     = (const float*)d_in[6];
    const float* bg     = (const float*)d_in[7];
    float* out = (float*)d_out;

    // ws layout (bf16): allEbf | Mt | WgT   (~51.6 MB)
    unsigned short* allEbf = (unsigned short*)d_ws;
    unsigned short* Mt     = allEbf + (size_t)NNODES * D_GNN;
    unsigned short* WgT    = Mt + D_GNN * D_GNN;

    (void)hipFuncSetAttribute((const void*)mega,
                              hipFuncAttributeMaxDynamicSharedMemorySize, 163840);

    conv_bf16<<<dim3(NNODES * D_GNN / 1024), dim3(256), 0, stream>>>(allE, allEbf);
    build_Mt <<<dim3(D_GNN),                 dim3(256), 0, stream>>>(Wq, Wk, Mt);
    conv_WgT <<<dim3(2 * D_GNN),             dim3(256), 0, stream>>>(Wg, WgT);
    mega     <<<dim3(NROWS / BROWS),         dim3(512), 163840, stream>>>(
        center, allEbf, nidx, nw, Mt, WgT, bg, out);
}